// Round 8
// baseline (387.305 us; speedup 1.0000x reference)
//
#include <hip/hip_runtime.h>

// ---------------- sizes ----------------
#define BATCH 16
#define L1 509
#define LP1 254
#define L4 250
#define LP4 125
#define L5 123
#define NPOS 3936
#define CA 5
#define OUT0_ELEMS 314880        // 16*5*3936
#define FLAT_K 19680
#define F1 1024
#define KSPLIT 8
#define KCHUNK 2460
#define LDS_BYTES (16 * KCHUNK * 4)   // 157,440 B
#define NBLK 256

// ws layout (floats): [0..15] barrier (cnt,gen at uint slots 0,1), then stats
#define P1S 16
#define P1Q (16 + 2048)
#define P4S (16 + 4096)
#define P4Q (16 + 6144)
#define P5S (16 + 8192)
#define P5Q (16 + 9216)
#define WSBUF (16 + 10240)

struct Params {
  const float *x, *c1w, *c1b, *bn1g, *bn1b;
  const float *c4w, *c4b, *bn4g, *bn4b;
  const float *c5w, *c5b, *bn5g, *bn5b;
  const float *a1wq, *a1bq, *a1wk, *a1bk, *a1wv, *a1bv, *a1ga;
  const float *a2wq, *a2bq, *a2wk, *a2bk, *a2wv, *a2bv, *a2ga;
  const float *f1w, *f1b, *g6, *b6, *f2w, *f2b;
  float *ws;
  float *out;
};

__device__ __forceinline__ float elu1(float x) {
  return x > 0.f ? x : (expf(x) - 1.f);
}

// software grid barrier: state zeroed by captured hipMemsetAsync each launch.
// read epoch -> publish -> arrive -> last block resets cnt, fences, bumps gen;
// others spin on gen. Device-scope atomics (cross-XCD safe).
__device__ __forceinline__ void gbar(unsigned* cnt, unsigned* gen) {
  __syncthreads();
  if (threadIdx.x == 0) {
    __threadfence();                       // publish this block's writes
    unsigned g = atomicAdd(gen, 0u);       // read current epoch FIRST
    if (atomicAdd(cnt, 1u) == NBLK - 1u) { // last arriver
      atomicExch(cnt, 0u);
      __threadfence();
      atomicAdd(gen, 1u);                  // release
    } else {
      while (atomicAdd(gen, 0u) == g) __builtin_amdgcn_s_sleep(2);
    }
    __threadfence();                       // acquire
  }
  __syncthreads();
}

// x2[b,c,n2] with n2 = h*123+w maps to out1[((b*5+c)*123+w)*32+h]
__device__ __forceinline__ float x2_load(const float* __restrict__ out1, int b, int c, int n2) {
  int h = n2 / 123, w = n2 - h * 123;
  return out1[((b * CA + c) * 123 + w) * 32 + h];
}

__global__ __launch_bounds__(512, 2) void k_fused(Params p) {
  extern __shared__ float lds[];
  const int gid = blockIdx.x, tid = threadIdx.x;
  const int lane = tid & 63;
  const int gt = gid * 512 + tid;          // 0..131071

  float* ws   = p.ws;
  unsigned* bcnt = (unsigned*)p.ws;        // ws[0]
  unsigned* bgen = ((unsigned*)p.ws) + 1;  // ws[1]
  float* y1   = ws + WSBUF;                // 16*32*509 = 260608
  float* p1   = y1 + 260608;               // 16*32*254 = 130048
  float* y4   = p1 + 130048;               // 16*64*250 = 256000
  float* p4   = y4 + 256000;               // 16*64*125 = 128000
  float* y5   = p4 + 128000;               // 16*32*123 = 62976
  float* out0 = y5 + 62976;                // 314880
  float* out1 = out0 + OUT0_ELEMS;         // 314880
  float* flat = out1 + OUT0_ELEMS;         // 314880
  float* hact = flat + OUT0_ELEMS;         // 16384
  float* part = hact + 16384;              // 8*1024*16 = 131072

  // ================= P1: conv1 (stride 2) + per-wave stats =================
  {
    int row = gt >> 8, i = gt & 255;       // 512 rows (b*32+co) x 256 threads
    int b = row >> 5, co = row & 31;
    const float* xp = p.x + b * 5105;      // 5*1021
    const float* wp = p.c1w + co * 25;
    float bias = p.c1b[co];
    float s = 0.f, q = 0.f;
    int l0 = i * 2;
    #pragma unroll
    for (int u = 0; u < 2; u++) {
      int l = l0 + u;
      if (l < L1) {
        float v = bias;
        #pragma unroll
        for (int ci = 0; ci < 5; ci++)
          #pragma unroll
          for (int tap = 0; tap < 5; tap++)
            v += xp[ci * 1021 + 2 * l + tap] * wp[ci * 5 + tap];
        y1[row * L1 + l] = v;
        s += v; q += v * v;
      }
    }
    #pragma unroll
    for (int off = 32; off > 0; off >>= 1) { s += __shfl_down(s, off); q += __shfl_down(q, off); }
    if (lane == 0) {
      int quarter = i >> 6;                // 4 waves per row
      ws[P1S + co * 64 + b * 4 + quarter] = s;
      ws[P1Q + co * 64 + b * 4 + quarter] = q;
    }
  }
  gbar(bcnt, bgen);

  // ================= P2: bn1 + elu + maxpool2 -> p1 =================
  {
    if (tid < 32) {
      int co = tid; float s = 0.f, q = 0.f;
      for (int j = 0; j < 64; j++) { s += ws[P1S + co * 64 + j]; q += ws[P1Q + co * 64 + j]; }
      float mean = s * (1.f / 8144.f);
      float var  = q * (1.f / 8144.f) - mean * mean;
      lds[co] = mean;
      lds[32 + co] = rsqrtf(var + 1e-5f) * p.bn1g[co];
    }
    __syncthreads();
    if (gt < 130048) {
      int row = gt / 254, i = gt - row * 254;
      int co = row & 31;
      float mean = lds[co], sc = lds[32 + co], bb = p.bn1b[co];
      const float* yp = y1 + row * L1;
      float a0 = (yp[2 * i] - mean) * sc + bb;
      float a1 = (yp[2 * i + 1] - mean) * sc + bb;
      p1[row * LP1 + i] = fmaxf(elu1(a0), elu1(a1));
    }
  }
  gbar(bcnt, bgen);

  // ================= P3: conv4 (k=5) + stats; p1[b] staged in LDS =================
  {
    int rowbase = gid * 4;                 // 1024 rows (b*64+co), 4 per block
    int b = rowbase >> 6;
    for (int j = tid; j < 32 * LP1; j += 512) lds[j] = p1[b * 32 * LP1 + j];
    __syncthreads();
    int r = tid >> 7, i = tid & 127;
    int co = (rowbase & 63) + r;
    const float* wp = p.c4w + co * 160;
    float bias = p.c4b[co];
    float s = 0.f, q = 0.f;
    #pragma unroll
    for (int u = 0; u < 2; u++) {
      int l = i + u * 128;
      if (l < L4) {
        float v = bias;
        for (int ci = 0; ci < 32; ci++) {
          #pragma unroll
          for (int tap = 0; tap < 5; tap++)
            v += lds[ci * LP1 + l + tap] * wp[ci * 5 + tap];
        }
        y4[(b * 64 + co) * L4 + l] = v;
        s += v; q += v * v;
      }
    }
    #pragma unroll
    for (int off = 32; off > 0; off >>= 1) { s += __shfl_down(s, off); q += __shfl_down(q, off); }
    if (lane == 0) {
      int wv = (tid >> 6) & 1;             // 2 waves per row
      ws[P4S + co * 32 + b * 2 + wv] = s;
      ws[P4Q + co * 32 + b * 2 + wv] = q;
    }
  }
  gbar(bcnt, bgen);

  // ================= P4: bn4 + elu + maxpool2 -> p4 =================
  {
    if (tid < 64) {
      int co = tid; float s = 0.f, q = 0.f;
      for (int j = 0; j < 32; j++) { s += ws[P4S + co * 32 + j]; q += ws[P4Q + co * 32 + j]; }
      float mean = s * (1.f / 4000.f);
      float var  = q * (1.f / 4000.f) - mean * mean;
      lds[co] = mean;
      lds[64 + co] = rsqrtf(var + 1e-5f) * p.bn4g[co];
    }
    __syncthreads();
    if (gt < 128000) {
      int row = gt / 125, i = gt - row * 125;
      int co = row & 63;
      float mean = lds[co], sc = lds[64 + co], bb = p.bn4b[co];
      const float* yp = y4 + row * L4;
      float a0 = (yp[2 * i] - mean) * sc + bb;
      float a1 = (yp[2 * i + 1] - mean) * sc + bb;
      p4[row * LP4 + i] = fmaxf(elu1(a0), elu1(a1));
    }
  }
  gbar(bcnt, bgen);

  // ================= P5: conv5 (k=3) + stats; p4[b] staged in LDS =================
  {
    if (gid < 128) {
      int rowbase = gid * 4;               // 512 rows (b*32+co), 4 per block
      int b = rowbase >> 5;
      for (int j = tid; j < 64 * LP4; j += 512) lds[j] = p4[b * 64 * LP4 + j];
      __syncthreads();
      int r = tid >> 7, i = tid & 127;
      int co = (rowbase & 31) + r;
      float s = 0.f, q = 0.f;
      if (i < L5) {
        float v = p.c5b[co];
        const float* wp = p.c5w + co * 192;
        for (int ci = 0; ci < 64; ci++) {
          #pragma unroll
          for (int tap = 0; tap < 3; tap++)
            v += lds[ci * LP4 + i + tap] * wp[ci * 3 + tap];
        }
        y5[(b * 32 + co) * L5 + i] = v;
        s = v; q = v * v;
      }
      #pragma unroll
      for (int off = 32; off > 0; off >>= 1) { s += __shfl_down(s, off); q += __shfl_down(q, off); }
      if (lane == 0) {
        int wv = (tid >> 6) & 1;
        ws[P5S + co * 32 + b * 2 + wv] = s;
        ws[P5Q + co * 32 + b * 2 + wv] = q;
      }
    }
  }
  gbar(bcnt, bgen);

  // ================= P6: bn5+elu; fast path writes flat, generic builds out0 =================
  float ga1 = p.a1ga[0], ga2 = p.a2ga[0];
  bool fastpath = (ga1 == 0.f) && (ga2 == 0.f);
  {
    if (tid < 32) {
      int co = tid; float s = 0.f, q = 0.f;
      for (int j = 0; j < 32; j++) { s += ws[P5S + co * 32 + j]; q += ws[P5Q + co * 32 + j]; }
      float mean = s * (1.f / 1968.f);
      float var  = q * (1.f / 1968.f) - mean * mean;
      lds[co] = mean;
      lds[32 + co] = rsqrtf(var + 1e-5f) * p.bn5g[co];
    }
    __syncthreads();
    if (fastpath) {
      // flat[b, c*3936 + h*123 + w] = elu(bn5(y5[b,h,w])), broadcast over c
      for (int idx = gt; idx < OUT0_ELEMS; idx += 131072) {
        int b = idx / FLAT_K;
        int rres = idx - b * FLAT_K;
        int n2 = rres % NPOS;
        int h = n2 / 123, w_ = n2 - h * 123;
        float v = (y5[(b * 32 + h) * L5 + w_] - lds[h]) * lds[32 + h] + p.bn5b[h];
        flat[idx] = elu1(v);
      }
    } else {
      // out0[b,c,w,h] layout: idx = ((b*5+c)*123+w)*32 + h
      for (int idx = gt; idx < OUT0_ELEMS; idx += 131072) {
        int h = idx & 31;
        int rest = idx >> 5;
        int w_ = rest % 123;
        int bc = rest / 123;
        int b = bc / 5;
        float v = (y5[(b * 32 + h) * L5 + w_] - lds[h]) * lds[32 + h] + p.bn5b[h];
        out0[idx] = elu1(v);
      }
    }
  }
  gbar(bcnt, bgen);

  // ================= generic attention path (only if some gamma != 0) =================
  if (!fastpath) {
    // ---- attn1 ----
    if (ga1 == 0.f) {
      for (int idx = gt; idx < OUT0_ELEMS; idx += 131072) out1[idx] = out0[idx];
    } else if (gt < BATCH * NPOS) {
      int b = gt / NPOS, n = gt - b * NPOS;
      const float* xb = out0 + b * CA * NPOS;
      float qv[CA];
      #pragma unroll
      for (int c = 0; c < CA; c++) {
        float s = p.a1bq[c];
        #pragma unroll
        for (int cc = 0; cc < CA; cc++) s += p.a1wq[c * CA + cc] * xb[cc * NPOS + n];
        qv[c] = s;
      }
      float mrun = -1e30f, lrun = 0.f, acc[CA] = {0, 0, 0, 0, 0};
      for (int m = 0; m < NPOS; m++) {
        float xm[CA];
        #pragma unroll
        for (int cc = 0; cc < CA; cc++) xm[cc] = xb[cc * NPOS + m];
        float e = 0.f;
        #pragma unroll
        for (int c = 0; c < CA; c++) {
          float kk = p.a1bk[c];
          #pragma unroll
          for (int cc = 0; cc < CA; cc++) kk += p.a1wk[c * CA + cc] * xm[cc];
          e += qv[c] * kk;
        }
        float nm = fmaxf(mrun, e);
        float corr = __expf(mrun - nm);
        float pp = __expf(e - nm);
        lrun = lrun * corr + pp;
        #pragma unroll
        for (int c = 0; c < CA; c++) {
          float vv = p.a1bv[c];
          #pragma unroll
          for (int cc = 0; cc < CA; cc++) vv += p.a1wv[c * CA + cc] * xm[cc];
          acc[c] = acc[c] * corr + pp * vv;
        }
        mrun = nm;
      }
      float invl = 1.f / lrun;
      #pragma unroll
      for (int c = 0; c < CA; c++)
        out1[b * CA * NPOS + c * NPOS + n] = ga1 * (acc[c] * invl) + xb[c * NPOS + n];
    }
    gbar(bcnt, bgen);
    // ---- attn2 (on transposed view) ----
    if (ga2 == 0.f) {
      for (int idx = gt; idx < OUT0_ELEMS; idx += 131072) {
        int b = idx / FLAT_K;
        int r = idx - b * FLAT_K;
        int c = r / NPOS;
        int n2 = r - c * NPOS;
        flat[idx] = x2_load(out1, b, c, n2);
      }
    } else if (gt < BATCH * NPOS) {
      int b = gt / NPOS, n = gt - b * NPOS;
      float qv[CA];
      #pragma unroll
      for (int c = 0; c < CA; c++) {
        float s = p.a2bq[c];
        #pragma unroll
        for (int cc = 0; cc < CA; cc++) s += p.a2wq[c * CA + cc] * x2_load(out1, b, cc, n);
        qv[c] = s;
      }
      float mrun = -1e30f, lrun = 0.f, acc[CA] = {0, 0, 0, 0, 0};
      for (int m = 0; m < NPOS; m++) {
        float xm[CA];
        #pragma unroll
        for (int cc = 0; cc < CA; cc++) xm[cc] = x2_load(out1, b, cc, m);
        float e = 0.f;
        #pragma unroll
        for (int c = 0; c < CA; c++) {
          float kk = p.a2bk[c];
          #pragma unroll
          for (int cc = 0; cc < CA; cc++) kk += p.a2wk[c * CA + cc] * xm[cc];
          e += qv[c] * kk;
        }
        float nm = fmaxf(mrun, e);
        float corr = __expf(mrun - nm);
        float pp = __expf(e - nm);
        lrun = lrun * corr + pp;
        #pragma unroll
        for (int c = 0; c < CA; c++) {
          float vv = p.a2bv[c];
          #pragma unroll
          for (int cc = 0; cc < CA; cc++) vv += p.a2wv[c * CA + cc] * xm[cc];
          acc[c] = acc[c] * corr + pp * vv;
        }
        mrun = nm;
      }
      float invl = 1.f / lrun;
      #pragma unroll
      for (int c = 0; c < CA; c++)
        flat[b * FLAT_K + c * NPOS + n] = ga2 * (acc[c] * invl) + x2_load(out1, b, c, n);
    }
    gbar(bcnt, bgen);
  }

  // ================= P7: fc1 split-K, activations in LDS, weights streamed =================
  {
    int og = gid >> 3, kc = gid & 7;       // 32 o-groups x 8 k-chunks
    int kbeg = kc * KCHUNK;
    for (int bb = 0; bb < 16; bb++) {
      const float4* src = (const float4*)(flat + bb * FLAT_K + kbeg);
      float4* dst = (float4*)(lds + bb * KCHUNK);
      for (int j = tid; j < KCHUNK / 4; j += 512) dst[j] = src[j];
    }
    __syncthreads();

    int wave = tid >> 6;
    int obase = og * 32 + wave * 4;
    const float* wrow0 = p.f1w + (size_t)obase * FLAT_K + kbeg;

    float acc[64];
    #pragma unroll
    for (int i = 0; i < 64; i++) acc[i] = 0.f;

    float4 wnxt[4];
    {
      int k0 = lane * 4;
      #pragma unroll
      for (int o = 0; o < 4; o++)
        wnxt[o] = *(const float4*)(wrow0 + o * FLAT_K + k0);
    }
    #pragma unroll 1
    for (int s = 0; s < 10; s++) {
      float4 wcur[4];
      #pragma unroll
      for (int o = 0; o < 4; o++) wcur[o] = wnxt[o];
      if (s < 9) {
        int kn = (s + 1) * 256 + lane * 4;
        if (kn >= KCHUNK) kn = 0;
        #pragma unroll
        for (int o = 0; o < 4; o++)
          wnxt[o] = *(const float4*)(wrow0 + o * FLAT_K + kn);
      }
      int kcur = s * 256 + lane * 4;
      if (kcur < KCHUNK) {
        #pragma unroll
        for (int bb = 0; bb < 16; bb++) {
          float4 f = *(const float4*)(lds + bb * KCHUNK + kcur);
          #pragma unroll
          for (int o = 0; o < 4; o++)
            acc[o * 16 + bb] += f.x * wcur[o].x + f.y * wcur[o].y +
                                f.z * wcur[o].z + f.w * wcur[o].w;
        }
      }
    }
    // transpose-reduce: lane l ends with total for (o=l>>4, b=l&15)
    #pragma unroll
    for (int round = 0; round < 6; round++) {
      const int bit = 1 << round;
      const int half = 32 >> round;
      #pragma unroll
      for (int i = 0; i < 32; i++) {
        if (i < half) {
          bool hi = (lane & bit) != 0;
          float keep  = hi ? acc[2 * i + 1] : acc[2 * i];
          float other = hi ? acc[2 * i]     : acc[2 * i + 1];
          acc[i] = keep + __shfl_xor(other, bit);
        }
      }
    }
    part[((size_t)kc * F1 + obase + (lane >> 4)) * 16 + (lane & 15)] = acc[0];
  }
  gbar(bcnt, bgen);

  // ================= P8: reduce partials + bias + bn6(batch) + elu -> hact =================
  {
    if (gt < F1 * 16) {
      int o = gt >> 4, bb = gt & 15;
      float s = 0.f;
      #pragma unroll
      for (int kc = 0; kc < KSPLIT; kc++) s += part[((size_t)kc * F1 + o) * 16 + bb];
      float h = s + p.f1b[o];
      float sum = h, sq = h * h;
      #pragma unroll
      for (int off = 1; off < 16; off <<= 1) {
        sum += __shfl_xor(sum, off);
        sq  += __shfl_xor(sq, off);
      }
      float mean = sum * (1.f / 16.f);
      float var  = sq * (1.f / 16.f) - mean * mean;
      float a = (h - mean) * rsqrtf(var + 1e-5f) * p.g6[o] + p.b6[o];
      hact[bb * F1 + o] = elu1(a);
    }
  }
  gbar(bcnt, bgen);

  // ================= P9: fc2 + softmax =================
  {
    if (gid < BATCH) {
      int b = gid;
      float acc[13];
      #pragma unroll
      for (int c = 0; c < 13; c++) acc[c] = 0.f;
      const float* hb = hact + b * F1;
      for (int k = tid; k < F1; k += 512) {
        float hv = hb[k];
        #pragma unroll
        for (int c = 0; c < 13; c++) acc[c] += hv * p.f2w[c * F1 + k];
      }
      #pragma unroll
      for (int c = 0; c < 13; c++)
        #pragma unroll
        for (int off = 1; off < 64; off <<= 1)
          acc[c] += __shfl_xor(acc[c], off);
      __syncthreads();
      int wv = tid >> 6;
      if (lane == 0) {
        #pragma unroll
        for (int c = 0; c < 13; c++) lds[wv * 13 + c] = acc[c];
      }
      __syncthreads();
      if (tid == 0) {
        float logit[13];
        float mx = -1e30f;
        #pragma unroll
        for (int c = 0; c < 13; c++) {
          float s = 0.f;
          for (int w8 = 0; w8 < 8; w8++) s += lds[w8 * 13 + c];
          logit[c] = s + p.f2b[c];
          mx = fmaxf(mx, logit[c]);
        }
        float s = 0.f;
        #pragma unroll
        for (int c = 0; c < 13; c++) { logit[c] = expf(logit[c] - mx); s += logit[c]; }
        float inv = 1.f / s;
        #pragma unroll
        for (int c = 0; c < 13; c++) p.out[b * 13 + c] = logit[c] * inv;
      }
    }
  }
}

// ---------------- launch ----------------
extern "C" void kernel_launch(void* const* d_in, const int* in_sizes, int n_in,
                              void* d_out, int out_size, void* d_ws, size_t ws_size,
                              hipStream_t stream) {
  Params prm;
  prm.x     = (const float*)d_in[0];
  prm.c1w   = (const float*)d_in[1];
  prm.c1b   = (const float*)d_in[2];
  prm.bn1g  = (const float*)d_in[3];
  prm.bn1b  = (const float*)d_in[4];
  prm.c4w   = (const float*)d_in[5];
  prm.c4b   = (const float*)d_in[6];
  prm.bn4g  = (const float*)d_in[7];
  prm.bn4b  = (const float*)d_in[8];
  prm.c5w   = (const float*)d_in[9];
  prm.c5b   = (const float*)d_in[10];
  prm.bn5g  = (const float*)d_in[11];
  prm.bn5b  = (const float*)d_in[12];
  prm.a1wq  = (const float*)d_in[13];
  prm.a1bq  = (const float*)d_in[14];
  prm.a1wk  = (const float*)d_in[15];
  prm.a1bk  = (const float*)d_in[16];
  prm.a1wv  = (const float*)d_in[17];
  prm.a1bv  = (const float*)d_in[18];
  prm.a1ga  = (const float*)d_in[19];
  prm.a2wq  = (const float*)d_in[20];
  prm.a2bq  = (const float*)d_in[21];
  prm.a2wk  = (const float*)d_in[22];
  prm.a2bk  = (const float*)d_in[23];
  prm.a2wv  = (const float*)d_in[24];
  prm.a2bv  = (const float*)d_in[25];
  prm.a2ga  = (const float*)d_in[26];
  prm.f1w   = (const float*)d_in[27];
  prm.f1b   = (const float*)d_in[28];
  prm.g6    = (const float*)d_in[29];
  prm.b6    = (const float*)d_in[30];
  prm.f2w   = (const float*)d_in[31];
  prm.f2b   = (const float*)d_in[32];
  prm.ws    = (float*)d_ws;
  prm.out   = (float*)d_out;

  hipFuncSetAttribute((const void*)k_fused,
                      hipFuncAttributeMaxDynamicSharedMemorySize, LDS_BYTES);

  // zero the software grid-barrier state (captured as a graph node, so it
  // re-arms on every replay)
  hipMemsetAsync(d_ws, 0, 64, stream);

  k_fused<<<dim3(NBLK), dim3(512), LDS_BYTES, stream>>>(prm);
}